// Round 1
// baseline (4701.842 us; speedup 1.0000x reference)
//
#include <hip/hip_runtime.h>

// ---------------------------------------------------------------------------
// MoE MLP (DeepseekV3-style) — round 1: correct fp32 baseline, sparse routing.
// T=8192 DIN=512 P=1024 I=1408 E=16 K=2 G=4 TG=2 IS=2816 A=29 scale=2.5
// Strategy: top-2-of-16 sparse dispatch (8x FLOP cut vs dense reference scan),
// 64x64x16 LDS-tiled fp32 GEMMs everywhere, exact-fp32 router (tie safety).
// ---------------------------------------------------------------------------

#define T_TOK 8192
#define DIN   512
#define PDIM  1024
#define IDIM  1408
#define NEXP  16
#define ISH   2816   // I * S
#define ADIM  29
#define SCALEF 2.5f

#define TILE 64
#define BK   16

__device__ __forceinline__ float silu_f(float v) {
  return v / (1.f + __expf(-v));
}

// ---------------------------------------------------------------------------
// Generic tiled GEMM: C[M,N] = act(A[M,K] @ B[K,N] + bias[N]).
// M multiple of 64 (guaranteed: M=T=8192), N,K multiples of 64/16.
// ---------------------------------------------------------------------------
template <int ACT>
__global__ __launch_bounds__(256) void gemm_tiled(
    const float* __restrict__ A, const float* __restrict__ B,
    const float* __restrict__ bias, float* __restrict__ C, int N, int Kd) {
  __shared__ float As[BK][TILE + 4];  // [k][m], +4 pad keeps 16B alignment, ~2-way free
  __shared__ float Bs[BK][TILE];      // [k][n], conflict-free

  const int tid = threadIdx.x;
  const int tx = tid & 15, ty = tid >> 4;
  const int bm = blockIdx.y * TILE, bn = blockIdx.x * TILE;
  const int arow = tid >> 2, acol = (tid & 3) * 4;
  const int brow = tid >> 4, bcol = (tid & 15) * 4;

  float acc[4][4] = {};

  for (int k0 = 0; k0 < Kd; k0 += BK) {
    float4 av = *(const float4*)&A[(size_t)(bm + arow) * Kd + k0 + acol];
    As[acol + 0][arow] = av.x; As[acol + 1][arow] = av.y;
    As[acol + 2][arow] = av.z; As[acol + 3][arow] = av.w;
    *(float4*)&Bs[brow][bcol] = *(const float4*)&B[(size_t)(k0 + brow) * N + bn + bcol];
    __syncthreads();
#pragma unroll
    for (int k = 0; k < BK; ++k) {
      float4 a4 = *(const float4*)&As[k][ty * 4];
      float4 b4 = *(const float4*)&Bs[k][tx * 4];
      float a[4] = {a4.x, a4.y, a4.z, a4.w};
      float b[4] = {b4.x, b4.y, b4.z, b4.w};
#pragma unroll
      for (int i = 0; i < 4; ++i)
#pragma unroll
        for (int j = 0; j < 4; ++j) acc[i][j] += a[i] * b[j];
    }
    __syncthreads();
  }

#pragma unroll
  for (int i = 0; i < 4; ++i) {
    float v[4];
#pragma unroll
    for (int j = 0; j < 4; ++j) {
      int n = bn + tx * 4 + j;
      float o = acc[i][j] + bias[n];
      v[j] = (ACT == 1) ? silu_f(o) : o;
    }
    float4 o4 = make_float4(v[0], v[1], v[2], v[3]);
    *(float4*)&C[(size_t)(bm + ty * 4 + i) * N + bn + tx * 4] = o4;
  }
}

// ---------------------------------------------------------------------------
// Fused gate/up SwiGLU GEMM: H[rows] = silu(Xg@Wg+bg) * (Xg@Wu+bu).
// GATHER=1: rows are per-expert slots (eoff ranges), A rows gathered via rowidx,
//           per-expert weights Wg+e*K*N.  GATHER=0: dense (shared experts).
// ---------------------------------------------------------------------------
template <int GATHER>
__global__ __launch_bounds__(256) void gateup_kernel(
    const float* __restrict__ X, const int* __restrict__ rowidx,
    const int* __restrict__ eoff, const float* __restrict__ Wg,
    const float* __restrict__ Bg, const float* __restrict__ Wu,
    const float* __restrict__ Bu, float* __restrict__ H, int Mfull, int N, int Kd) {
  const int e = blockIdx.z;
  const int m0 = GATHER ? eoff[e] : 0;
  const int m1 = GATHER ? eoff[e + 1] : Mfull;
  const int bm = m0 + blockIdx.y * TILE;
  if (bm >= m1) return;
  const int bn = blockIdx.x * TILE;
  const float* wg = Wg + (size_t)e * Kd * N;
  const float* wu = Wu + (size_t)e * Kd * N;
  const float* bg = Bg + (size_t)e * N;
  const float* bu = Bu + (size_t)e * N;

  __shared__ float As[BK][TILE + 4];
  __shared__ float Bgs[BK][TILE];
  __shared__ float Bus[BK][TILE];

  const int tid = threadIdx.x;
  const int tx = tid & 15, ty = tid >> 4;
  const int arow = tid >> 2, acol = (tid & 3) * 4;
  const int brow = tid >> 4, bcol = (tid & 15) * 4;

  const int ga = bm + arow;
  const bool av = ga < m1;
  const int srow = av ? (GATHER ? rowidx[ga] : ga) : 0;
  const float* aptr = X + (size_t)srow * Kd;

  float accg[4][4] = {}, accu[4][4] = {};

  for (int k0 = 0; k0 < Kd; k0 += BK) {
    float4 avv = av ? *(const float4*)(aptr + k0 + acol) : make_float4(0.f, 0.f, 0.f, 0.f);
    As[acol + 0][arow] = avv.x; As[acol + 1][arow] = avv.y;
    As[acol + 2][arow] = avv.z; As[acol + 3][arow] = avv.w;
    *(float4*)&Bgs[brow][bcol] = *(const float4*)&wg[(size_t)(k0 + brow) * N + bn + bcol];
    *(float4*)&Bus[brow][bcol] = *(const float4*)&wu[(size_t)(k0 + brow) * N + bn + bcol];
    __syncthreads();
#pragma unroll
    for (int k = 0; k < BK; ++k) {
      float4 a4 = *(const float4*)&As[k][ty * 4];
      float4 g4 = *(const float4*)&Bgs[k][tx * 4];
      float4 u4 = *(const float4*)&Bus[k][tx * 4];
      float a[4] = {a4.x, a4.y, a4.z, a4.w};
      float g[4] = {g4.x, g4.y, g4.z, g4.w};
      float u[4] = {u4.x, u4.y, u4.z, u4.w};
#pragma unroll
      for (int i = 0; i < 4; ++i)
#pragma unroll
        for (int j = 0; j < 4; ++j) {
          accg[i][j] += a[i] * g[j];
          accu[i][j] += a[i] * u[j];
        }
    }
    __syncthreads();
  }

#pragma unroll
  for (int i = 0; i < 4; ++i) {
    int row = bm + ty * 4 + i;
    if (row < m1) {
      float v[4];
#pragma unroll
      for (int j = 0; j < 4; ++j) {
        int n = bn + tx * 4 + j;
        v[j] = silu_f(accg[i][j] + bg[n]) * (accu[i][j] + bu[n]);
      }
      float4 o4 = make_float4(v[0], v[1], v[2], v[3]);
      *(float4*)&H[(size_t)row * N + bn + tx * 4] = o4;
    }
  }
}

// ---------------------------------------------------------------------------
// Routed down-proj + scatter: RP[slot][tok] = wgt * (H[rows]@Wd[e] + bd[e]).
// Deterministic: each (slot,token) written exactly once (every token has
// exactly 2 distinct experts, so RP is fully covered — no zero-init needed).
// ---------------------------------------------------------------------------
__global__ __launch_bounds__(256) void down_scatter(
    const float* __restrict__ H, const int* __restrict__ eoff,
    const int* __restrict__ tok, const int* __restrict__ slk,
    const float* __restrict__ wgt, const float* __restrict__ Wd,
    const float* __restrict__ Bd, float* __restrict__ RP, int N, int Kd) {
  const int e = blockIdx.z;
  const int m0 = eoff[e], m1 = eoff[e + 1];
  const int bm = m0 + blockIdx.y * TILE;
  if (bm >= m1) return;
  const int bn = blockIdx.x * TILE;
  const float* wd = Wd + (size_t)e * Kd * N;
  const float* bd = Bd + (size_t)e * N;

  __shared__ float As[BK][TILE + 4];
  __shared__ float Bs[BK][TILE];

  const int tid = threadIdx.x;
  const int tx = tid & 15, ty = tid >> 4;
  const int arow = tid >> 2, acol = (tid & 3) * 4;
  const int brow = tid >> 4, bcol = (tid & 15) * 4;

  const int ga = bm + arow;
  const bool av = ga < m1;
  const float* aptr = H + (size_t)(av ? ga : 0) * Kd;

  float acc[4][4] = {};

  for (int k0 = 0; k0 < Kd; k0 += BK) {
    float4 avv = av ? *(const float4*)(aptr + k0 + acol) : make_float4(0.f, 0.f, 0.f, 0.f);
    As[acol + 0][arow] = avv.x; As[acol + 1][arow] = avv.y;
    As[acol + 2][arow] = avv.z; As[acol + 3][arow] = avv.w;
    *(float4*)&Bs[brow][bcol] = *(const float4*)&wd[(size_t)(k0 + brow) * N + bn + bcol];
    __syncthreads();
#pragma unroll
    for (int k = 0; k < BK; ++k) {
      float4 a4 = *(const float4*)&As[k][ty * 4];
      float4 b4 = *(const float4*)&Bs[k][tx * 4];
      float a[4] = {a4.x, a4.y, a4.z, a4.w};
      float b[4] = {b4.x, b4.y, b4.z, b4.w};
#pragma unroll
      for (int i = 0; i < 4; ++i)
#pragma unroll
        for (int j = 0; j < 4; ++j) acc[i][j] += a[i] * b[j];
    }
    __syncthreads();
  }

#pragma unroll
  for (int i = 0; i < 4; ++i) {
    int row = bm + ty * 4 + i;
    if (row < m1) {
      int t = tok[row];
      int s = slk[row];
      float w = wgt[row];
      float v[4];
#pragma unroll
      for (int j = 0; j < 4; ++j) v[j] = (acc[i][j] + bd[bn + tx * 4 + j]) * w;
      float4 o4 = make_float4(v[0], v[1], v[2], v[3]);
      *(float4*)&RP[((size_t)s * T_TOK + t) * PDIM + bn + tx * 4] = o4;
    }
  }
}

// ---------------------------------------------------------------------------
// Router: exact fp32 replica of DeepseekV3TopkRouter. One wave per token.
// Tie-breaking: strict '>' argmax scans == jax top_k lowest-index-first.
// ---------------------------------------------------------------------------
__global__ __launch_bounds__(64) void router_kernel(
    const float* __restrict__ xp, const float* __restrict__ Wr,
    const float* __restrict__ br, const float* __restrict__ bc,
    int* __restrict__ tidx, float* __restrict__ tw, int* __restrict__ counts) {
  const int t = blockIdx.x;
  const int lane = threadIdx.x;
  __shared__ float xs[PDIM];
  __shared__ float sc[NEXP];

  const float4* src = (const float4*)(xp + (size_t)t * PDIM);
  for (int i = lane; i < PDIM / 4; i += 64) ((float4*)xs)[i] = src[i];
  __syncthreads();

  const int e = lane & 15, q = lane >> 4;
  float s = 0.f;
  for (int p = q * 256; p < q * 256 + 256; ++p) s += xs[p] * Wr[p * NEXP + e];
  s += __shfl_xor(s, 16);
  s += __shfl_xor(s, 32);
  if (lane < NEXP) sc[lane] = 1.f / (1.f + expf(-(s + br[lane])));
  __syncthreads();

  if (lane == 0) {
    float scr[NEXP], sfc[NEXP];
#pragma unroll
    for (int i = 0; i < NEXP; ++i) { scr[i] = sc[i]; sfc[i] = scr[i] + bc[i]; }
    // group scores = sum of top-2 within each group of 4
    float gs[4];
#pragma unroll
    for (int g = 0; g < 4; ++g) {
      int b = g * 4, i1 = -1;
      float v1 = -1e30f, v2 = -1e30f;
      for (int j = 0; j < 4; ++j) if (sfc[b + j] > v1) { v1 = sfc[b + j]; i1 = j; }
      for (int j = 0; j < 4; ++j) if (j != i1 && sfc[b + j] > v2) v2 = sfc[b + j];
      gs[g] = v1 + v2;
    }
    int g1 = 0, g2 = -1;
    float gv1 = -1e30f, gv2 = -1e30f;
    for (int j = 0; j < 4; ++j) if (gs[j] > gv1) { gv1 = gs[j]; g1 = j; }
    for (int j = 0; j < 4; ++j) if (j != g1 && gs[j] > gv2) { gv2 = gs[j]; g2 = j; }
    float msk[NEXP];
#pragma unroll
    for (int i = 0; i < NEXP; ++i) {
      int gg = i >> 2;
      msk[i] = (gg == g1 || gg == g2) ? sfc[i] : 0.f;
    }
    int i1 = 0, i2 = -1;
    float v1 = -1e30f, v2 = -1e30f;
    for (int i = 0; i < NEXP; ++i) if (msk[i] > v1) { v1 = msk[i]; i1 = i; }
    for (int i = 0; i < NEXP; ++i) if (i != i1 && msk[i] > v2) { v2 = msk[i]; i2 = i; }
    float w1 = scr[i1], w2 = scr[i2];
    float sw = w1 + w2 + 1e-20f;
    w1 = w1 / sw * SCALEF;
    w2 = w2 / sw * SCALEF;
    tidx[2 * t] = i1; tidx[2 * t + 1] = i2;
    tw[2 * t] = w1; tw[2 * t + 1] = w2;
    atomicAdd(&counts[i1], 1);
    atomicAdd(&counts[i2], 1);
  }
}

__global__ void prefix_kernel(const int* __restrict__ counts, int* __restrict__ off,
                              int* __restrict__ fill) {
  if (threadIdx.x == 0) {
    int a = 0;
    for (int e = 0; e < NEXP; ++e) { off[e] = a; a += counts[e]; }
    off[NEXP] = a;
  }
  if (threadIdx.x < NEXP) fill[threadIdx.x] = 0;
}

__global__ void build_dispatch(const int* __restrict__ tidx, const float* __restrict__ tw,
                               const int* __restrict__ off, int* __restrict__ fill,
                               int* __restrict__ tok, int* __restrict__ slk,
                               float* __restrict__ wgt) {
  int t = blockIdx.x * blockDim.x + threadIdx.x;
  if (t >= T_TOK) return;
#pragma unroll
  for (int k = 0; k < 2; ++k) {
    int e = tidx[2 * t + k];
    int pos = atomicAdd(&fill[e], 1);
    int g = off[e] + pos;
    tok[g] = t; slk[g] = k; wgt[g] = tw[2 * t + k];
  }
}

// combined += RP[0] + RP[1]   (in place on the shared-expert output)
__global__ __launch_bounds__(256) void combine_kernel(float* __restrict__ comb,
                                                      const float* __restrict__ rp) {
  size_t i = (size_t)blockIdx.x * blockDim.x + threadIdx.x;
  float4 a = ((const float4*)comb)[i];
  float4 r0 = ((const float4*)rp)[i];
  float4 r1 = ((const float4*)(rp + (size_t)T_TOK * PDIM))[i];
  a.x += r0.x + r1.x; a.y += r0.y + r1.y; a.z += r0.z + r1.z; a.w += r0.w + r1.w;
  ((float4*)comb)[i] = a;
}

// ---------------------------------------------------------------------------
// Final tiny GEMM: out[T,29] = mid[T,1408] @ W2[1408,29] + b2. N=29 too small
// for the tile kernel; 64-token blocks, K-chunked LDS staging, transposed mid.
// ---------------------------------------------------------------------------
__global__ __launch_bounds__(256) void out_mlp2(const float* __restrict__ mid,
                                                const float* __restrict__ W2,
                                                const float* __restrict__ b2,
                                                float* __restrict__ out) {
  __shared__ float ms[TILE][TILE + 1];  // [k][tok]
  __shared__ float w2s[TILE][32];
  const int tid = threadIdx.x;
  const int tokl = tid & 63, g = tid >> 6;  // g in 0..3
  const int t0 = blockIdx.x * TILE;
  float acc[8] = {};

  for (int k0 = 0; k0 < IDIM; k0 += TILE) {
#pragma unroll
    for (int it = 0; it < 4; ++it) {
      int rr = tid >> 2;
      int cc = (tid & 3) * 4 + it * 16;
      float4 v = *(const float4*)&mid[(size_t)(t0 + rr) * IDIM + k0 + cc];
      ms[cc + 0][rr] = v.x; ms[cc + 1][rr] = v.y;
      ms[cc + 2][rr] = v.z; ms[cc + 3][rr] = v.w;
    }
    for (int idx = tid; idx < TILE * 32; idx += 256) {
      int r2 = idx >> 5, a = idx & 31;
      w2s[r2][a] = (a < ADIM) ? W2[(size_t)(k0 + r2) * ADIM + a] : 0.f;
    }
    __syncthreads();
#pragma unroll 8
    for (int kk = 0; kk < TILE; ++kk) {
      float m = ms[kk][tokl];
#pragma unroll
      for (int j = 0; j < 8; ++j) acc[j] += m * w2s[kk][g + 4 * j];
    }
    __syncthreads();
  }
#pragma unroll
  for (int j = 0; j < 8; ++j) {
    int a = g + 4 * j;
    if (a < ADIM) out[(size_t)(t0 + tokl) * ADIM + a] = acc[j] + b2[a];
  }
}

// ---------------------------------------------------------------------------
extern "C" void kernel_launch(void* const* d_in, const int* in_sizes, int n_in,
                              void* d_out, int out_size, void* d_ws, size_t ws_size,
                              hipStream_t stream) {
  const float* x   = (const float*)d_in[0];
  const float* Wp  = (const float*)d_in[1];
  const float* bp  = (const float*)d_in[2];
  const float* Wr  = (const float*)d_in[3];
  const float* br  = (const float*)d_in[4];
  const float* bc  = (const float*)d_in[5];
  const float* Wg  = (const float*)d_in[6];
  const float* bg  = (const float*)d_in[7];
  const float* Wu  = (const float*)d_in[8];
  const float* bu  = (const float*)d_in[9];
  const float* Wd  = (const float*)d_in[10];
  const float* bd  = (const float*)d_in[11];
  const float* Wsg = (const float*)d_in[12];
  const float* bsg = (const float*)d_in[13];
  const float* Wsu = (const float*)d_in[14];
  const float* bsu = (const float*)d_in[15];
  const float* Wsd = (const float*)d_in[16];
  const float* bsd = (const float*)d_in[17];
  const float* W1  = (const float*)d_in[18];
  const float* b1  = (const float*)d_in[19];
  const float* W2  = (const float*)d_in[20];
  const float* b2  = (const float*)d_in[21];
  float* out = (float*)d_out;

  // workspace layout (floats): ~227 MB total
  float* ws   = (float*)d_ws;
  float* xp   = ws;                                   // T*P      (32 MB)
  float* comb = xp + (size_t)T_TOK * PDIM;            // T*P      (32 MB)
  float* Hbuf = comb + (size_t)T_TOK * PDIM;          // T*ISH == 2T*I (88 MB)
  float* RP   = Hbuf + (size_t)T_TOK * ISH;           // 2*T*P    (64 MB)
  int*   tidx = (int*)(RP + 2 * (size_t)T_TOK * PDIM);
  float* tw   = (float*)(tidx + 2 * T_TOK);
  int*   counts = (int*)(tw + 2 * T_TOK);
  int*   off    = counts + NEXP;
  int*   fill   = off + NEXP + 1;
  int*   tok    = fill + NEXP;
  int*   slk    = tok + 2 * T_TOK;
  float* wgt    = (float*)(slk + 2 * T_TOK);

  hipMemsetAsync(counts, 0, NEXP * sizeof(int), stream);

  // 1) xp = x @ Wp + bp
  gemm_tiled<0><<<dim3(PDIM / TILE, T_TOK / TILE), 256, 0, stream>>>(x, Wp, bp, xp, PDIM, DIN);

  // 2) router (fp32 exact) + dispatch lists
  router_kernel<<<T_TOK, 64, 0, stream>>>(xp, Wr, br, bc, tidx, tw, counts);
  prefix_kernel<<<1, 64, 0, stream>>>(counts, off, fill);
  build_dispatch<<<T_TOK / 256, 256, 0, stream>>>(tidx, tw, off, fill, tok, slk, wgt);

  // 3) shared experts: Hbuf = swiglu(xp), comb = Hbuf @ Wsd + bsd
  gateup_kernel<0><<<dim3(ISH / TILE, T_TOK / TILE, 1), 256, 0, stream>>>(
      xp, nullptr, nullptr, Wsg, bsg, Wsu, bsu, Hbuf, T_TOK, ISH, PDIM);
  gemm_tiled<0><<<dim3(PDIM / TILE, T_TOK / TILE), 256, 0, stream>>>(Hbuf, Wsd, bsd, comb, PDIM, ISH);

  // 4) routed experts (sparse): gathered gate/up, then down + scatter to RP
  gateup_kernel<1><<<dim3(IDIM / TILE, T_TOK / TILE, NEXP), 256, 0, stream>>>(
      xp, tok, off, Wg, bg, Wu, bu, Hbuf, 0, IDIM, PDIM);
  down_scatter<<<dim3(PDIM / TILE, T_TOK / TILE, NEXP), 256, 0, stream>>>(
      Hbuf, off, tok, slk, wgt, Wd, bd, RP, PDIM, IDIM);

  // 5) combined = shared + routed0 + routed1
  combine_kernel<<<(T_TOK * PDIM / 4) / 256, 256, 0, stream>>>(comb, RP);

  // 6) output MLP: mid = silu(comb@W1+b1) (reuse Hbuf), out = mid@W2+b2
  gemm_tiled<1><<<dim3(IDIM / TILE, T_TOK / TILE), 256, 0, stream>>>(comb, W1, b1, Hbuf, IDIM, PDIM);
  out_mlp2<<<T_TOK / TILE, 256, 0, stream>>>(Hbuf, W2, b2, out);
}

// Round 4
// 2651.243 us; speedup vs baseline: 1.7734x; 1.7734x over previous
//
#include <hip/hip_runtime.h>

// ---------------------------------------------------------------------------
// MoE MLP (DeepseekV3-style) — round 4: split-bf16 MFMA, workspace <= ~193 MB.
// T=8192 DIN=512 P=1024 I=1408 E=16 K=2 ISH=2816 A=29 scale=2.5
// - Router + xp GEMM exact fp32 (bit-identical routing to round 1).
// - Heavy GEMMs: on-the-fly split x=hi+lo bf16; C = Ah*Bh + Ah*Bl + Al*Bh via
//   mfma_f32_16x16x32_bf16 (fp32 accum) -> ~2^-16 rel err.
// - Weights streamed f32, split+transposed during LDS staging (no pre-pass).
// - Fused gate+up kernel (SwiGLU epilogue writes pre-split H planes).
// Workspace layout (bytes):
//   bufX [0, 33.5M): xp f32 -> later shared-out/combined f32
//   bufH [33.5M, 125.8M): H hi/lo planes -> later mid f32
//   bufR [125.8M, 192.9M): RP (2 slots of [T][P] f32)
//   meta [192.9M, +~0.2M)
// ---------------------------------------------------------------------------

#define T_TOK 8192
#define DIN   512
#define PDIM  1024
#define IDIM  1408
#define NEXP  16
#define ISH   2816
#define ADIM  29
#define SCALEF 2.5f

#define TILE 64
#define BKF  16
#define BM   128
#define BN   128
#define BKK  32

using short8v = __attribute__((ext_vector_type(8))) short;
using float4v = __attribute__((ext_vector_type(4))) float;

__device__ __forceinline__ float silu_f(float v) {
  return v / (1.f + __expf(-v));
}

// split two consecutive fp32 (x=even k, y=odd k) into packed bf16 hi/lo uints
__device__ __forceinline__ void pack2(float x, float y, uint& h, uint& l) {
  uint ux = __float_as_uint(x), uy = __float_as_uint(y);
  uint hx = ux & 0xffff0000u, hy = uy & 0xffff0000u;
  float rx = x - __uint_as_float(hx);
  float ry = y - __uint_as_float(hy);
  h = (hx >> 16) | hy;
  l = (__float_as_uint(rx) >> 16) | (__float_as_uint(ry) & 0xffff0000u);
}

__device__ __forceinline__ void split1(float f, ushort& h, ushort& l) {
  uint u = __float_as_uint(f);
  uint hb = u & 0xffff0000u;
  h = (ushort)(hb >> 16);
  float fl = f - __uint_as_float(hb);
  l = (ushort)(__float_as_uint(fl) >> 16);
}

// ---------------------------------------------------------------------------
// fp32 tiled GEMM (xp only — keeps router inputs bit-identical to round 1)
// ---------------------------------------------------------------------------
__global__ __launch_bounds__(256) void gemm_tiled_f32(
    const float* __restrict__ A, const float* __restrict__ B,
    const float* __restrict__ bias, float* __restrict__ C, int N, int Kd) {
  __shared__ float As[BKF][TILE + 4];
  __shared__ float Bs[BKF][TILE];
  const int tid = threadIdx.x;
  const int tx = tid & 15, ty = tid >> 4;
  const int bm = blockIdx.y * TILE, bn = blockIdx.x * TILE;
  const int arow = tid >> 2, acol = (tid & 3) * 4;
  const int brow = tid >> 4, bcol = (tid & 15) * 4;
  float acc[4][4] = {};
  for (int k0 = 0; k0 < Kd; k0 += BKF) {
    float4 av = *(const float4*)&A[(size_t)(bm + arow) * Kd + k0 + acol];
    As[acol + 0][arow] = av.x; As[acol + 1][arow] = av.y;
    As[acol + 2][arow] = av.z; As[acol + 3][arow] = av.w;
    *(float4*)&Bs[brow][bcol] = *(const float4*)&B[(size_t)(k0 + brow) * N + bn + bcol];
    __syncthreads();
#pragma unroll
    for (int k = 0; k < BKF; ++k) {
      float4 a4 = *(const float4*)&As[k][ty * 4];
      float4 b4 = *(const float4*)&Bs[k][tx * 4];
      float a[4] = {a4.x, a4.y, a4.z, a4.w};
      float b[4] = {b4.x, b4.y, b4.z, b4.w};
#pragma unroll
      for (int i = 0; i < 4; ++i)
#pragma unroll
        for (int j = 0; j < 4; ++j) acc[i][j] += a[i] * b[j];
    }
    __syncthreads();
  }
#pragma unroll
  for (int i = 0; i < 4; ++i) {
    float v[4];
#pragma unroll
    for (int j = 0; j < 4; ++j) v[j] = acc[i][j] + bias[bn + tx * 4 + j];
    *(float4*)&C[(size_t)(bm + ty * 4 + i) * N + bn + tx * 4] =
        make_float4(v[0], v[1], v[2], v[3]);
  }
}

// ---------------------------------------------------------------------------
// Unified split-bf16 MFMA GEMM.
//   AKIND: 0 = A is f32 [rows][K], split on the fly
//          1 = A is pre-split bf16 planes Ahi/Alo [rows][K]
//   GATHER: 0 dense rows [0,M); 1 expert range + row-gather via rowidx;
//           2 expert range, direct rows (may over-read; epilogue guarded)
//   FUSED: 1 = two B tensors (gate/up)
//   EPI: 0 Cout=acc+bias | 1 Cout=silu(acc+bias)
//        2 H planes = split(silu(accg+b1)*(accu+b2))   [FUSED only]
//        3 RP[slk][tok] = (acc+bias)*wgt
// Block: 512 threads = 8 waves (2m x 4n); wave tile 64m x 32n per tensor.
// LDS rows padded to 20 uints (80 B) -> conflict-free-ish ds_read_b128.
// ---------------------------------------------------------------------------
template <int AKIND, int GATHER, int FUSED, int EPI>
__global__ __launch_bounds__(512, 2) void moe_gemm(
    const float* __restrict__ Af32, const ushort* __restrict__ Ahi,
    const ushort* __restrict__ Alo,
    const float* __restrict__ B1, const float* __restrict__ bias1,
    const float* __restrict__ B2, const float* __restrict__ bias2,
    int bstride,
    float* __restrict__ Cout, ushort* __restrict__ Hhi, ushort* __restrict__ Hlo,
    const int* __restrict__ eoff, const int* __restrict__ rowidx,
    const int* __restrict__ tokv, const int* __restrict__ slkv,
    const float* __restrict__ wgtv, float* __restrict__ RP,
    int M, int N, int K) {
  const int e = GATHER ? blockIdx.z : 0;
  int m0 = 0, m1 = M;
  if (GATHER) { m0 = eoff[e]; m1 = eoff[e + 1]; }
  const int bm = m0 + blockIdx.y * BM;
  if (GATHER && bm >= m1) return;
  const int bn = blockIdx.x * BN;
  const float* Bp1 = B1 + (size_t)e * K * N;
  const float* Bp2 = FUSED ? (B2 + (size_t)e * K * N) : nullptr;
  const float* bp1 = bias1 + (size_t)e * bstride;
  const float* bp2 = FUSED ? (bias2 + (size_t)e * bstride) : nullptr;

  __shared__ uint As_h[BM][20], As_l[BM][20];
  __shared__ uint Bs_h[FUSED + 1][BN][20], Bs_l[FUSED + 1][BN][20];

  const int tid = threadIdx.x;
  const int lane = tid & 63, wv = tid >> 6;
  const int wm = (wv & 1) * 64, wn = (wv >> 1) * 32;

  // A staging: row = tid>>2 (0..127), k-chunk = (tid&3)*8
  const int sar = tid >> 2, sak = (tid & 3) * 8;
  int arow = bm + sar;
  int ar;
  if (GATHER == 1) ar = (arow < m1) ? rowidx[arow] : 0;
  else ar = arow;  // GATHER==2 over-read lands in allocated ws; rows guarded at EPI
  const size_t abase = (size_t)ar * K + sak;

  // B staging: k-pair = (tid&15)*2, n-quad = (tid>>4)*4
  const int sbk = (tid & 15) * 2, sbn = (tid >> 4) * 4;
  const int jb = sbk >> 1;

  uint4 rah, ral;            // staged A (packed hi/lo)
  uint4 rbh[FUSED + 1], rbl[FUSED + 1];

  auto load_tile = [&](int k0) {
    if (AKIND == 0) {
      float4 a0 = *(const float4*)(Af32 + abase + k0);
      float4 a1 = *(const float4*)(Af32 + abase + k0 + 4);
      pack2(a0.x, a0.y, rah.x, ral.x);
      pack2(a0.z, a0.w, rah.y, ral.y);
      pack2(a1.x, a1.y, rah.z, ral.z);
      pack2(a1.z, a1.w, rah.w, ral.w);
    } else {
      rah = *(const uint4*)(Ahi + abase + k0);
      ral = *(const uint4*)(Alo + abase + k0);
    }
#pragma unroll
    for (int p = 0; p <= FUSED; ++p) {
      const float* Bp = (p == 0) ? Bp1 : Bp2;
      float4 b0 = *(const float4*)(Bp + (size_t)(k0 + sbk) * N + bn + sbn);
      float4 b1 = *(const float4*)(Bp + (size_t)(k0 + sbk + 1) * N + bn + sbn);
      pack2(b0.x, b1.x, rbh[p].x, rbl[p].x);
      pack2(b0.y, b1.y, rbh[p].y, rbl[p].y);
      pack2(b0.z, b1.z, rbh[p].z, rbl[p].z);
      pack2(b0.w, b1.w, rbh[p].w, rbl[p].w);
    }
  };

  float4v acc[FUSED + 1][4][2] = {};
  const int fr = lane & 15, fk = (lane >> 4) * 4;

  load_tile(0);
  for (int k0 = 0;; k0 += BKK) {
    __syncthreads();
    *(uint4*)&As_h[sar][sak >> 1] = rah;
    *(uint4*)&As_l[sar][sak >> 1] = ral;
#pragma unroll
    for (int p = 0; p <= FUSED; ++p) {
      Bs_h[p][sbn + 0][jb] = rbh[p].x; Bs_h[p][sbn + 1][jb] = rbh[p].y;
      Bs_h[p][sbn + 2][jb] = rbh[p].z; Bs_h[p][sbn + 3][jb] = rbh[p].w;
      Bs_l[p][sbn + 0][jb] = rbl[p].x; Bs_l[p][sbn + 1][jb] = rbl[p].y;
      Bs_l[p][sbn + 2][jb] = rbl[p].z; Bs_l[p][sbn + 3][jb] = rbl[p].w;
    }
    __syncthreads();
    if (k0 + BKK < K) load_tile(k0 + BKK);  // prefetch overlaps MFMA

    short8v ah[4], al[4];
#pragma unroll
    for (int i = 0; i < 4; ++i) {
      ah[i] = *(const short8v*)&As_h[wm + i * 16 + fr][fk];
      al[i] = *(const short8v*)&As_l[wm + i * 16 + fr][fk];
    }
#pragma unroll
    for (int p = 0; p <= FUSED; ++p)
#pragma unroll
      for (int j = 0; j < 2; ++j) {
        short8v bh = *(const short8v*)&Bs_h[p][wn + j * 16 + fr][fk];
        short8v bl = *(const short8v*)&Bs_l[p][wn + j * 16 + fr][fk];
#pragma unroll
        for (int i = 0; i < 4; ++i) {
          acc[p][i][j] = __builtin_amdgcn_mfma_f32_16x16x32_bf16(ah[i], bh, acc[p][i][j], 0, 0, 0);
          acc[p][i][j] = __builtin_amdgcn_mfma_f32_16x16x32_bf16(ah[i], bl, acc[p][i][j], 0, 0, 0);
          acc[p][i][j] = __builtin_amdgcn_mfma_f32_16x16x32_bf16(al[i], bh, acc[p][i][j], 0, 0, 0);
        }
      }
    if (k0 + BKK >= K) break;
  }

  // epilogue: C col = lane&15, row = (lane>>4)*4 + reg  [m89-verified]
  const int crow = (lane >> 4) * 4, ccol = lane & 15;
#pragma unroll
  for (int i = 0; i < 4; ++i) {
    const int rb = bm + wm + i * 16 + crow;
#pragma unroll
    for (int j = 0; j < 2; ++j) {
      const int col = bn + wn + j * 16 + ccol;
      const float bv1 = bp1[col];
      const float bv2 = FUSED ? bp2[col] : 0.f;
#pragma unroll
      for (int r = 0; r < 4; ++r) {
        const int row = rb + r;
        if (GATHER && row >= m1) continue;
        if (EPI == 2) {
          float g = acc[0][i][j][r] + bv1;
          float u = acc[1][i][j][r] + bv2;
          float h = silu_f(g) * u;
          ushort hh, ll;
          split1(h, hh, ll);
          Hhi[(size_t)row * N + col] = hh;
          Hlo[(size_t)row * N + col] = ll;
        } else {
          float v = acc[0][i][j][r] + bv1;
          if (EPI == 0) {
            Cout[(size_t)row * N + col] = v;
          } else if (EPI == 1) {
            Cout[(size_t)row * N + col] = silu_f(v);
          } else {  // EPI == 3
            float w = wgtv[row];
            int t = tokv[row], s = slkv[row];
            RP[((size_t)s * T_TOK + t) * PDIM + col] = v * w;
          }
        }
      }
    }
  }
}

// ---------------------------------------------------------------------------
// Router (fp32 exact, unchanged from round 1) + dispatch builders
// ---------------------------------------------------------------------------
__global__ __launch_bounds__(64) void router_kernel(
    const float* __restrict__ xp, const float* __restrict__ Wr,
    const float* __restrict__ br, const float* __restrict__ bc,
    int* __restrict__ tidx, float* __restrict__ tw, int* __restrict__ counts) {
  const int t = blockIdx.x;
  const int lane = threadIdx.x;
  __shared__ float xs[PDIM];
  __shared__ float sc[NEXP];
  const float4* src = (const float4*)(xp + (size_t)t * PDIM);
  for (int i = lane; i < PDIM / 4; i += 64) ((float4*)xs)[i] = src[i];
  __syncthreads();
  const int e = lane & 15, q = lane >> 4;
  float s = 0.f;
  for (int p = q * 256; p < q * 256 + 256; ++p) s += xs[p] * Wr[p * NEXP + e];
  s += __shfl_xor(s, 16);
  s += __shfl_xor(s, 32);
  if (lane < NEXP) sc[lane] = 1.f / (1.f + expf(-(s + br[lane])));
  __syncthreads();
  if (lane == 0) {
    float scr[NEXP], sfc[NEXP];
#pragma unroll
    for (int i = 0; i < NEXP; ++i) { scr[i] = sc[i]; sfc[i] = scr[i] + bc[i]; }
    float gs[4];
#pragma unroll
    for (int g = 0; g < 4; ++g) {
      int b = g * 4, i1 = -1;
      float v1 = -1e30f, v2 = -1e30f;
      for (int j = 0; j < 4; ++j) if (sfc[b + j] > v1) { v1 = sfc[b + j]; i1 = j; }
      for (int j = 0; j < 4; ++j) if (j != i1 && sfc[b + j] > v2) v2 = sfc[b + j];
      gs[g] = v1 + v2;
    }
    int g1 = 0, g2 = -1;
    float gv1 = -1e30f, gv2 = -1e30f;
    for (int j = 0; j < 4; ++j) if (gs[j] > gv1) { gv1 = gs[j]; g1 = j; }
    for (int j = 0; j < 4; ++j) if (j != g1 && gs[j] > gv2) { gv2 = gs[j]; g2 = j; }
    float msk[NEXP];
#pragma unroll
    for (int i = 0; i < NEXP; ++i) {
      int gg = i >> 2;
      msk[i] = (gg == g1 || gg == g2) ? sfc[i] : 0.f;
    }
    int i1 = 0, i2 = -1;
    float v1 = -1e30f, v2 = -1e30f;
    for (int i = 0; i < NEXP; ++i) if (msk[i] > v1) { v1 = msk[i]; i1 = i; }
    for (int i = 0; i < NEXP; ++i) if (i != i1 && msk[i] > v2) { v2 = msk[i]; i2 = i; }
    float w1 = scr[i1], w2 = scr[i2];
    float sw = w1 + w2 + 1e-20f;
    w1 = w1 / sw * SCALEF;
    w2 = w2 / sw * SCALEF;
    tidx[2 * t] = i1; tidx[2 * t + 1] = i2;
    tw[2 * t] = w1; tw[2 * t + 1] = w2;
    atomicAdd(&counts[i1], 1);
    atomicAdd(&counts[i2], 1);
  }
}

__global__ void prefix_kernel(const int* __restrict__ counts, int* __restrict__ off,
                              int* __restrict__ fill) {
  if (threadIdx.x == 0) {
    int a = 0;
    for (int e = 0; e < NEXP; ++e) { off[e] = a; a += counts[e]; }
    off[NEXP] = a;
  }
  if (threadIdx.x < NEXP) fill[threadIdx.x] = 0;
}

__global__ void build_dispatch(const int* __restrict__ tidx, const float* __restrict__ tw,
                               const int* __restrict__ off, int* __restrict__ fill,
                               int* __restrict__ tok, int* __restrict__ slk,
                               float* __restrict__ wgt) {
  int t = blockIdx.x * blockDim.x + threadIdx.x;
  if (t >= T_TOK) return;
#pragma unroll
  for (int k = 0; k < 2; ++k) {
    int e = tidx[2 * t + k];
    int pos = atomicAdd(&fill[e], 1);
    int g = off[e] + pos;
    tok[g] = t; slk[g] = k; wgt[g] = tw[2 * t + k];
  }
}

__global__ __launch_bounds__(256) void combine_kernel(float* __restrict__ comb,
                                                      const float* __restrict__ rp) {
  size_t i = (size_t)blockIdx.x * blockDim.x + threadIdx.x;
  float4 a = ((const float4*)comb)[i];
  float4 r0 = ((const float4*)rp)[i];
  float4 r1 = ((const float4*)(rp + (size_t)T_TOK * PDIM))[i];
  a.x += r0.x + r1.x; a.y += r0.y + r1.y; a.z += r0.z + r1.z; a.w += r0.w + r1.w;
  ((float4*)comb)[i] = a;
}

__global__ __launch_bounds__(256) void out_mlp2(const float* __restrict__ mid,
                                                const float* __restrict__ W2,
                                                const float* __restrict__ b2,
                                                float* __restrict__ out) {
  __shared__ float ms[TILE][TILE + 1];
  __shared__ float w2s[TILE][32];
  const int tid = threadIdx.x;
  const int tokl = tid & 63, g = tid >> 6;
  const int t0 = blockIdx.x * TILE;
  float acc[8] = {};
  for (int k0 = 0; k0 < IDIM; k0 += TILE) {
#pragma unroll
    for (int it = 0; it < 4; ++it) {
      int rr = tid >> 2;
      int cc = (tid & 3) * 4 + it * 16;
      float4 v = *(const float4*)&mid[(size_t)(t0 + rr) * IDIM + k0 + cc];
      ms[cc + 0][rr] = v.x; ms[cc + 1][rr] = v.y;
      ms[cc + 2][rr] = v.z; ms[cc + 3][rr] = v.w;
    }
    for (int idx = tid; idx < TILE * 32; idx += 256) {
      int r2 = idx >> 5, a = idx & 31;
      w2s[r2][a] = (a < ADIM) ? W2[(size_t)(k0 + r2) * ADIM + a] : 0.f;
    }
    __syncthreads();
#pragma unroll 8
    for (int kk = 0; kk < TILE; ++kk) {
      float m = ms[kk][tokl];
#pragma unroll
      for (int j = 0; j < 8; ++j) acc[j] += m * w2s[kk][g + 4 * j];
    }
    __syncthreads();
  }
#pragma unroll
  for (int j = 0; j < 8; ++j) {
    int a = g + 4 * j;
    if (a < ADIM) out[(size_t)(t0 + tokl) * ADIM + a] = acc[j] + b2[a];
  }
}

// ---------------------------------------------------------------------------
extern "C" void kernel_launch(void* const* d_in, const int* in_sizes, int n_in,
                              void* d_out, int out_size, void* d_ws, size_t ws_size,
                              hipStream_t stream) {
  const float* x   = (const float*)d_in[0];
  const float* Wp  = (const float*)d_in[1];
  const float* bp  = (const float*)d_in[2];
  const float* Wr  = (const float*)d_in[3];
  const float* br  = (const float*)d_in[4];
  const float* bc  = (const float*)d_in[5];
  const float* Wg  = (const float*)d_in[6];
  const float* bg  = (const float*)d_in[7];
  const float* Wu  = (const float*)d_in[8];
  const float* bu  = (const float*)d_in[9];
  const float* Wd  = (const float*)d_in[10];
  const float* bd  = (const float*)d_in[11];
  const float* Wsg = (const float*)d_in[12];
  const float* bsg = (const float*)d_in[13];
  const float* Wsu = (const float*)d_in[14];
  const float* bsu = (const float*)d_in[15];
  const float* Wsd = (const float*)d_in[16];
  const float* bsd = (const float*)d_in[17];
  const float* W1  = (const float*)d_in[18];
  const float* b1  = (const float*)d_in[19];
  const float* W2  = (const float*)d_in[20];
  const float* b2  = (const float*)d_in[21];
  float* out = (float*)d_out;

  // ---- workspace (total ~193.2 MB) ----
  char* w8 = (char*)d_ws;
  const size_t SZ_XP = (size_t)T_TOK * PDIM * 4;          // 33,554,432
  const size_t SZ_HP = (size_t)2 * T_TOK * IDIM * 2;      // 46,137,344 per plane
  const size_t SZ_RP = (size_t)2 * T_TOK * PDIM * 4;      // 67,108,864
  float*  xp   = (float*)w8;                               // -> later comb f32
  ushort* Hh   = (ushort*)(w8 + SZ_XP);
  ushort* Hl   = (ushort*)(w8 + SZ_XP + SZ_HP);
  float*  RP   = (float*)(w8 + SZ_XP + 2 * SZ_HP);
  char*   meta = w8 + SZ_XP + 2 * SZ_HP + SZ_RP;
  int*    tidx  = (int*)meta;
  float*  tw    = (float*)(tidx + 2 * T_TOK);
  int*    counts= (int*)(tw + 2 * T_TOK);
  int*    off   = counts + NEXP;
  int*    fill  = off + NEXP + 1;
  int*    tok   = fill + NEXP;
  int*    slk   = tok + 2 * T_TOK;
  float*  wgt   = (float*)(slk + 2 * T_TOK);

  float* comb = xp;                 // shared-out + combine, reuses xp region
  float* mid  = (float*)Hh;         // W1 output reuses H region (46.1 MB)

  hipMemsetAsync(counts, 0, NEXP * sizeof(int), stream);

  // 1) xp = x @ Wp + bp (exact fp32)
  gemm_tiled_f32<<<dim3(PDIM / TILE, T_TOK / TILE), 256, 0, stream>>>(x, Wp, bp, xp, PDIM, DIN);

  // 2) router + dispatch lists
  router_kernel<<<T_TOK, 64, 0, stream>>>(xp, Wr, br, bc, tidx, tw, counts);
  prefix_kernel<<<1, 64, 0, stream>>>(counts, off, fill);
  build_dispatch<<<T_TOK / 256, 256, 0, stream>>>(tidx, tw, off, fill, tok, slk, wgt);

  const dim3 blk(512);

  // 3) routed experts: fused gate/up -> H planes [16384][IDIM]
  moe_gemm<0, 1, 1, 2><<<dim3(IDIM / BN, 64, NEXP), blk, 0, stream>>>(
      xp, nullptr, nullptr, Wg, bg, Wu, bu, IDIM,
      nullptr, Hh, Hl, off, tok, nullptr, nullptr, nullptr, nullptr,
      0, IDIM, PDIM);

  // 4) routed down + scatter: RP[slk][tok] = (H @ Wd[e] + bd)*wgt
  moe_gemm<1, 2, 0, 3><<<dim3(PDIM / BN, 64, NEXP), blk, 0, stream>>>(
      nullptr, Hh, Hl, Wd, bd, nullptr, nullptr, PDIM,
      nullptr, nullptr, nullptr, off, nullptr, tok, slk, wgt, RP,
      0, PDIM, IDIM);

  // 5) shared experts: fused gate/up -> H planes [8192][ISH] (reuse)
  moe_gemm<0, 0, 1, 2><<<dim3(ISH / BN, T_TOK / BM, 1), blk, 0, stream>>>(
      xp, nullptr, nullptr, Wsg, bsg, Wsu, bsu, 0,
      nullptr, Hh, Hl, nullptr, nullptr, nullptr, nullptr, nullptr, nullptr,
      T_TOK, ISH, PDIM);

  // 6) shared down -> comb (xp region; xp dead after step 5)
  moe_gemm<1, 0, 0, 0><<<dim3(PDIM / BN, T_TOK / BM, 1), blk, 0, stream>>>(
      nullptr, Hh, Hl, Wsd, bsd, nullptr, nullptr, 0,
      comb, nullptr, nullptr, nullptr, nullptr, nullptr, nullptr, nullptr, nullptr,
      T_TOK, PDIM, ISH);

  // 7) comb += RP0 + RP1
  combine_kernel<<<(T_TOK * PDIM / 4) / 256, 256, 0, stream>>>(comb, RP);

  // 8) mid = silu(comb @ W1 + b1)  (H region reuse)
  moe_gemm<0, 0, 0, 1><<<dim3(IDIM / BN, T_TOK / BM, 1), blk, 0, stream>>>(
      comb, nullptr, nullptr, W1, b1, nullptr, nullptr, 0,
      mid, nullptr, nullptr, nullptr, nullptr, nullptr, nullptr, nullptr, nullptr,
      T_TOK, IDIM, PDIM);

  // 9) out = mid @ W2 + b2
  out_mlp2<<<T_TOK / TILE, 256, 0, stream>>>(mid, W2, b2, out);
}

// Round 5
// 2013.704 us; speedup vs baseline: 2.3349x; 1.3166x over previous
//
#include <hip/hip_runtime.h>

// ---------------------------------------------------------------------------
// MoE MLP (DeepseekV3-style) — round 5: pre-rounded bf16 weight planes (RNE),
// 2-mult split-A MFMA (Ah*B + Al*B), unfused gate/up (in-place SwiGLU),
// atomicAdd routed combine. Workspace ~206 MB (< proven 221 MB from R1).
// T=8192 DIN=512 P=1024 I=1408 E=16 ISH=2816 A=29 scale=2.5
// Router + xp GEMM exact fp32 (routing decisions bit-identical to R1/R4).
// ---------------------------------------------------------------------------

#define T_TOK 8192
#define DIN   512
#define PDIM  1024
#define IDIM  1408
#define NEXP  16
#define ISH   2816
#define ADIM  29
#define SCALEF 2.5f

#define TILE 64
#define BKF  16
#define BM   128
#define BN   128
#define BKK  32

using short8v = __attribute__((ext_vector_type(8))) short;
using float4v = __attribute__((ext_vector_type(4))) float;

__device__ __forceinline__ float silu_f(float v) {
  return v / (1.f + __expf(-v));
}

// split two consecutive fp32 into packed bf16 hi/lo uints (hi=trunc, lo=resid)
__device__ __forceinline__ void pack2(float x, float y, uint& h, uint& l) {
  uint ux = __float_as_uint(x), uy = __float_as_uint(y);
  uint hx = ux & 0xffff0000u, hy = uy & 0xffff0000u;
  float rx = x - __uint_as_float(hx);
  float ry = y - __uint_as_float(hy);
  h = (hx >> 16) | hy;
  l = (__float_as_uint(rx) >> 16) | (__float_as_uint(ry) & 0xffff0000u);
}

// round-to-nearest-even two fp32 -> packed bf16 pair
__device__ __forceinline__ uint rne2(float a, float b) {
  uint ua = __float_as_uint(a), ub = __float_as_uint(b);
  ua += 0x7fffu + ((ua >> 16) & 1u);
  ub += 0x7fffu + ((ub >> 16) & 1u);
  return (ua >> 16) | (ub & 0xffff0000u);
}

// ---------------------------------------------------------------------------
// fp32 tiled GEMM (xp only — keeps router inputs bit-identical to round 1)
// ---------------------------------------------------------------------------
__global__ __launch_bounds__(256) void gemm_tiled_f32(
    const float* __restrict__ A, const float* __restrict__ B,
    const float* __restrict__ bias, float* __restrict__ C, int N, int Kd) {
  __shared__ float As[BKF][TILE + 4];
  __shared__ float Bs[BKF][TILE];
  const int tid = threadIdx.x;
  const int tx = tid & 15, ty = tid >> 4;
  const int bm = blockIdx.y * TILE, bn = blockIdx.x * TILE;
  const int arow = tid >> 2, acol = (tid & 3) * 4;
  const int brow = tid >> 4, bcol = (tid & 15) * 4;
  float acc[4][4] = {};
  for (int k0 = 0; k0 < Kd; k0 += BKF) {
    float4 av = *(const float4*)&A[(size_t)(bm + arow) * Kd + k0 + acol];
    As[acol + 0][arow] = av.x; As[acol + 1][arow] = av.y;
    As[acol + 2][arow] = av.z; As[acol + 3][arow] = av.w;
    *(float4*)&Bs[brow][bcol] = *(const float4*)&B[(size_t)(k0 + brow) * N + bn + bcol];
    __syncthreads();
#pragma unroll
    for (int k = 0; k < BKF; ++k) {
      float4 a4 = *(const float4*)&As[k][ty * 4];
      float4 b4 = *(const float4*)&Bs[k][tx * 4];
      float a[4] = {a4.x, a4.y, a4.z, a4.w};
      float b[4] = {b4.x, b4.y, b4.z, b4.w};
#pragma unroll
      for (int i = 0; i < 4; ++i)
#pragma unroll
        for (int j = 0; j < 4; ++j) acc[i][j] += a[i] * b[j];
    }
    __syncthreads();
  }
#pragma unroll
  for (int i = 0; i < 4; ++i) {
    float v[4];
#pragma unroll
    for (int j = 0; j < 4; ++j) v[j] = acc[i][j] + bias[bn + tx * 4 + j];
    *(float4*)&C[(size_t)(bm + ty * 4 + i) * N + bn + tx * 4] =
        make_float4(v[0], v[1], v[2], v[3]);
  }
}

// ---------------------------------------------------------------------------
// Weight pre-round + transpose: W[e][K][N] f32 -> plane[e][K/32][N][32] bf16
// (RNE). Layout is k-tile-major so a GEMM block's (bn,k0) stage is one
// contiguous 128x32 chunk, copied uint4->LDS with zero VALU.
// ---------------------------------------------------------------------------
__global__ __launch_bounds__(256) void roundtrans(
    const float* __restrict__ W, ushort* __restrict__ Pl, int K, int N) {
  const float* src = W + (size_t)blockIdx.z * K * N;
  ushort* dst = Pl + (size_t)blockIdx.z * ((size_t)K * N);
  __shared__ float ts[64][65];
  const int k0 = blockIdx.x * 64, n0 = blockIdx.y * 64;
  const int tid = threadIdx.x;
  const int r = tid >> 4, c4 = (tid & 15) * 4;
#pragma unroll
  for (int p = 0; p < 4; ++p) {
    float4 v = *(const float4*)&src[(size_t)(k0 + p * 16 + r) * N + n0 + c4];
    ts[p * 16 + r][c4 + 0] = v.x; ts[p * 16 + r][c4 + 1] = v.y;
    ts[p * 16 + r][c4 + 2] = v.z; ts[p * 16 + r][c4 + 3] = v.w;
  }
  __syncthreads();
  // 128 output chunks (n 0..63 x ktile 0..1); thread t writes 16 bf16
  const int c = tid >> 1, n = c >> 1, kt = c & 1, hf = tid & 1;
  uint o[8];
#pragma unroll
  for (int q = 0; q < 8; ++q) {
    int k = kt * 32 + hf * 16 + q * 2;
    o[q] = rne2(ts[k][n], ts[k + 1][n]);
  }
  ushort* op = dst + ((size_t)((k0 >> 5) + kt) * N + n0 + n) * 32 + hf * 16;
  *(uint4*)op = make_uint4(o[0], o[1], o[2], o[3]);
  *(uint4*)(op + 8) = make_uint4(o[4], o[5], o[6], o[7]);
}

// ---------------------------------------------------------------------------
// Split-A bf16 MFMA GEMM: C = split(A) @ plane(B) + bias.
//   A f32 [rows][K] split on the fly (hi+lo exact); B pre-rounded plane.
//   GATHER: 0 dense; 1 expert range + row-gather; 2 expert range direct.
//   EPI: 0 C=acc+b | 1 C=silu(C_in)*(acc+b) in-place (C_in==Cout) |
//        2 atomicAdd(Comb[tok[row]], (acc+b)*wgt[row]) | 3 C=silu(acc+b)
// Block 512 thr = 8 waves (4m x 2n), wave tile 32m x 64n. LDS 30 KB.
// ---------------------------------------------------------------------------
template <int GATHER, int EPI>
__global__ __launch_bounds__(512, 2) void moe_gemm2(
    const float* __restrict__ A, const ushort* __restrict__ Bpl,
    const float* __restrict__ bias, int bstride,
    float* __restrict__ Cout,
    const int* __restrict__ eoff, const int* __restrict__ rowidx,
    const int* __restrict__ tokv, const float* __restrict__ wgtv,
    float* __restrict__ Comb,
    int M, int N, int K) {
  const int e = GATHER ? blockIdx.z : 0;
  int m0 = 0, m1 = M;
  if (GATHER) { m0 = eoff[e]; m1 = eoff[e + 1]; }
  const int bm = m0 + blockIdx.y * BM;
  if (GATHER && bm >= m1) return;
  const int bn = blockIdx.x * BN;
  const ushort* bpl = Bpl + (size_t)e * K * N;
  const float* bp = bias + (size_t)e * bstride;

  __shared__ uint As_h[BM][20], As_l[BM][20];  // 32 bf16/row in 16 uints, pad 20
  __shared__ uint Bs[BN][20];

  const int tid = threadIdx.x;
  const int lane = tid & 63, wv = tid >> 6;
  const int wm = (wv & 3) * 32, wn = (wv >> 2) * 64;

  // A staging: row tid>>2, k-offset (tid&3)*8 (f32)
  const int sar = tid >> 2, sak = (tid & 3) * 8;
  const int arow = bm + sar;
  int ar;
  if (GATHER == 1) ar = (arow < m1) ? rowidx[arow] : 0;
  else ar = arow;  // GATHER==2: possible over-read stays inside d_ws; EPI-guarded
  const size_t abase = (size_t)ar * K + sak;
  // B staging: contiguous chunk; thread covers row bn+(tid>>2), k (tid&3)*8
  const size_t bthr = ((size_t)bn + sar) * 32 + (size_t)(tid & 3) * 8;

  uint4 rah, ral, rbv;
  auto load_tile = [&](int k0) {
    float4 a0 = *(const float4*)(A + abase + k0);
    float4 a1 = *(const float4*)(A + abase + k0 + 4);
    pack2(a0.x, a0.y, rah.x, ral.x);
    pack2(a0.z, a0.w, rah.y, ral.y);
    pack2(a1.x, a1.y, rah.z, ral.z);
    pack2(a1.z, a1.w, rah.w, ral.w);
    rbv = *(const uint4*)(bpl + (size_t)(k0 >> 5) * N * 32 + bthr);
  };

  float4v acc[2][4] = {};
  const int fr = lane & 15, fk = (lane >> 4) * 4;

  load_tile(0);
  for (int k0 = 0;; k0 += BKK) {
    __syncthreads();
    *(uint4*)&As_h[sar][sak >> 1] = rah;
    *(uint4*)&As_l[sar][sak >> 1] = ral;
    *(uint4*)&Bs[sar][(tid & 3) * 4] = rbv;
    __syncthreads();
    if (k0 + BKK < K) load_tile(k0 + BKK);  // prefetch overlaps MFMA

    short8v ah[2], al[2];
#pragma unroll
    for (int i = 0; i < 2; ++i) {
      ah[i] = *(const short8v*)&As_h[wm + i * 16 + fr][fk];
      al[i] = *(const short8v*)&As_l[wm + i * 16 + fr][fk];
    }
#pragma unroll
    for (int j = 0; j < 4; ++j) {
      short8v bv = *(const short8v*)&Bs[wn + j * 16 + fr][fk];
#pragma unroll
      for (int i = 0; i < 2; ++i) {
        acc[i][j] = __builtin_amdgcn_mfma_f32_16x16x32_bf16(ah[i], bv, acc[i][j], 0, 0, 0);
        acc[i][j] = __builtin_amdgcn_mfma_f32_16x16x32_bf16(al[i], bv, acc[i][j], 0, 0, 0);
      }
    }
    if (k0 + BKK >= K) break;
  }

  // epilogue: C col = lane&15, row = (lane>>4)*4 + reg  [m89-verified]
  const int crow = (lane >> 4) * 4, ccol = lane & 15;
#pragma unroll
  for (int i = 0; i < 2; ++i) {
    const int rb = bm + wm + i * 16 + crow;
#pragma unroll
    for (int j = 0; j < 4; ++j) {
      const int col = bn + wn + j * 16 + ccol;
      const float bv = bp[col];
#pragma unroll
      for (int r = 0; r < 4; ++r) {
        const int row = rb + r;
        if (GATHER && row >= m1) continue;
        float v = acc[i][j][r] + bv;
        if (EPI == 0) {
          Cout[(size_t)row * N + col] = v;
        } else if (EPI == 1) {
          float g = Cout[(size_t)row * N + col];
          Cout[(size_t)row * N + col] = silu_f(g) * v;
        } else if (EPI == 2) {
          atomicAdd(&Comb[(size_t)tokv[row] * PDIM + col], v * wgtv[row]);
        } else {
          Cout[(size_t)row * N + col] = silu_f(v);
        }
      }
    }
  }
}

// ---------------------------------------------------------------------------
// Router (fp32 exact, unchanged from round 1) + dispatch builders
// ---------------------------------------------------------------------------
__global__ __launch_bounds__(64) void router_kernel(
    const float* __restrict__ xp, const float* __restrict__ Wr,
    const float* __restrict__ br, const float* __restrict__ bc,
    int* __restrict__ tidx, float* __restrict__ tw, int* __restrict__ counts) {
  const int t = blockIdx.x;
  const int lane = threadIdx.x;
  __shared__ float xs[PDIM];
  __shared__ float sc[NEXP];
  const float4* src = (const float4*)(xp + (size_t)t * PDIM);
  for (int i = lane; i < PDIM / 4; i += 64) ((float4*)xs)[i] = src[i];
  __syncthreads();
  const int e = lane & 15, q = lane >> 4;
  float s = 0.f;
  for (int p = q * 256; p < q * 256 + 256; ++p) s += xs[p] * Wr[p * NEXP + e];
  s += __shfl_xor(s, 16);
  s += __shfl_xor(s, 32);
  if (lane < NEXP) sc[lane] = 1.f / (1.f + expf(-(s + br[lane])));
  __syncthreads();
  if (lane == 0) {
    float scr[NEXP], sfc[NEXP];
#pragma unroll
    for (int i = 0; i < NEXP; ++i) { scr[i] = sc[i]; sfc[i] = scr[i] + bc[i]; }
    float gs[4];
#pragma unroll
    for (int g = 0; g < 4; ++g) {
      int b = g * 4, i1 = -1;
      float v1 = -1e30f, v2 = -1e30f;
      for (int j = 0; j < 4; ++j) if (sfc[b + j] > v1) { v1 = sfc[b + j]; i1 = j; }
      for (int j = 0; j < 4; ++j) if (j != i1 && sfc[b + j] > v2) v2 = sfc[b + j];
      gs[g] = v1 + v2;
    }
    int g1 = 0, g2 = -1;
    float gv1 = -1e30f, gv2 = -1e30f;
    for (int j = 0; j < 4; ++j) if (gs[j] > gv1) { gv1 = gs[j]; g1 = j; }
    for (int j = 0; j < 4; ++j) if (j != g1 && gs[j] > gv2) { gv2 = gs[j]; g2 = j; }
    float msk[NEXP];
#pragma unroll
    for (int i = 0; i < NEXP; ++i) {
      int gg = i >> 2;
      msk[i] = (gg == g1 || gg == g2) ? sfc[i] : 0.f;
    }
    int i1 = 0, i2 = -1;
    float v1 = -1e30f, v2 = -1e30f;
    for (int i = 0; i < NEXP; ++i) if (msk[i] > v1) { v1 = msk[i]; i1 = i; }
    for (int i = 0; i < NEXP; ++i) if (i != i1 && msk[i] > v2) { v2 = msk[i]; i2 = i; }
    float w1 = scr[i1], w2 = scr[i2];
    float sw = w1 + w2 + 1e-20f;
    w1 = w1 / sw * SCALEF;
    w2 = w2 / sw * SCALEF;
    tidx[2 * t] = i1; tidx[2 * t + 1] = i2;
    tw[2 * t] = w1; tw[2 * t + 1] = w2;
    atomicAdd(&counts[i1], 1);
    atomicAdd(&counts[i2], 1);
  }
}

__global__ void prefix_kernel(const int* __restrict__ counts, int* __restrict__ off,
                              int* __restrict__ fill) {
  if (threadIdx.x == 0) {
    int a = 0;
    for (int e = 0; e < NEXP; ++e) { off[e] = a; a += counts[e]; }
    off[NEXP] = a;
  }
  if (threadIdx.x < NEXP) fill[threadIdx.x] = 0;
}

__global__ void build_dispatch(const int* __restrict__ tidx, const float* __restrict__ tw,
                               const int* __restrict__ off, int* __restrict__ fill,
                               int* __restrict__ tok, float* __restrict__ wgt) {
  int t = blockIdx.x * blockDim.x + threadIdx.x;
  if (t >= T_TOK) return;
#pragma unroll
  for (int k = 0; k < 2; ++k) {
    int e = tidx[2 * t + k];
    int pos = atomicAdd(&fill[e], 1);
    int g = off[e] + pos;
    tok[g] = t; wgt[g] = tw[2 * t + k];
  }
}

__global__ __launch_bounds__(256) void out_mlp2(const float* __restrict__ mid,
                                                const float* __restrict__ W2,
                                                const float* __restrict__ b2,
                                                float* __restrict__ out) {
  __shared__ float ms[TILE][TILE + 1];
  __shared__ float w2s[TILE][32];
  const int tid = threadIdx.x;
  const int tokl = tid & 63, g = tid >> 6;
  const int t0 = blockIdx.x * TILE;
  float acc[8] = {};
  for (int k0 = 0; k0 < IDIM; k0 += TILE) {
#pragma unroll
    for (int it = 0; it < 4; ++it) {
      int rr = tid >> 2;
      int cc = (tid & 3) * 4 + it * 16;
      float4 v = *(const float4*)&mid[(size_t)(t0 + rr) * IDIM + k0 + cc];
      ms[cc + 0][rr] = v.x; ms[cc + 1][rr] = v.y;
      ms[cc + 2][rr] = v.z; ms[cc + 3][rr] = v.w;
    }
    for (int idx = tid; idx < TILE * 32; idx += 256) {
      int r2 = idx >> 5, a = idx & 31;
      w2s[r2][a] = (a < ADIM) ? W2[(size_t)(k0 + r2) * ADIM + a] : 0.f;
    }
    __syncthreads();
#pragma unroll 8
    for (int kk = 0; kk < TILE; ++kk) {
      float m = ms[kk][tokl];
#pragma unroll
      for (int j = 0; j < 8; ++j) acc[j] += m * w2s[kk][g + 4 * j];
    }
    __syncthreads();
  }
#pragma unroll
  for (int j = 0; j < 8; ++j) {
    int a = g + 4 * j;
    if (a < ADIM) out[(size_t)(t0 + tokl) * ADIM + a] = acc[j] + b2[a];
  }
}

// ---------------------------------------------------------------------------
extern "C" void kernel_launch(void* const* d_in, const int* in_sizes, int n_in,
                              void* d_out, int out_size, void* d_ws, size_t ws_size,
                              hipStream_t stream) {
  const float* x   = (const float*)d_in[0];
  const float* Wp  = (const float*)d_in[1];
  const float* bp  = (const float*)d_in[2];
  const float* Wr  = (const float*)d_in[3];
  const float* br  = (const float*)d_in[4];
  const float* bc  = (const float*)d_in[5];
  const float* Wg  = (const float*)d_in[6];
  const float* bg  = (const float*)d_in[7];
  const float* Wu  = (const float*)d_in[8];
  const float* bu  = (const float*)d_in[9];
  const float* Wd  = (const float*)d_in[10];
  const float* bd  = (const float*)d_in[11];
  const float* Wsg = (const float*)d_in[12];
  const float* bsg = (const float*)d_in[13];
  const float* Wsu = (const float*)d_in[14];
  const float* bsu = (const float*)d_in[15];
  const float* Wsd = (const float*)d_in[16];
  const float* bsd = (const float*)d_in[17];
  const float* W1  = (const float*)d_in[18];
  const float* b1  = (const float*)d_in[19];
  const float* W2  = (const float*)d_in[20];
  const float* b2  = (const float*)d_in[21];
  float* out = (float*)d_out;

  // ---- workspace (~206 MB; R1's 221 MB footprint passed, so ws >= 221 MB) ----
  char* w8 = (char*)d_ws;
  const size_t SZ_XP = (size_t)T_TOK * PDIM * 4;            //  33.5 MB
  const size_t SZ_GH = (size_t)2 * T_TOK * IDIM * 4;        //  92.3 MB
  const size_t SZ_WP = (size_t)NEXP * PDIM * IDIM * 2;      //  46.1 MB
  float*  xp   = (float*)w8;                                 // xp f32
  float*  comb = (float*)(w8 + SZ_XP);                       // combined f32
  float*  GH   = (float*)(w8 + 2 * SZ_XP);                   // G/H (in place), later mid
  ushort* Wpl  = (ushort*)(w8 + 2 * SZ_XP + SZ_GH);          // current weight plane
  char*   meta = w8 + 2 * SZ_XP + SZ_GH + SZ_WP;
  int*    tidx  = (int*)meta;
  float*  tw    = (float*)(tidx + 2 * T_TOK);
  int*    counts= (int*)(tw + 2 * T_TOK);
  int*    off   = counts + NEXP;
  int*    fill  = off + NEXP + 1;
  int*    tok   = fill + NEXP;
  float*  wgt   = (float*)(tok + 2 * T_TOK);

  hipMemsetAsync(counts, 0, NEXP * sizeof(int), stream);

  // 1) xp = x @ Wp + bp (exact fp32)
  gemm_tiled_f32<<<dim3(PDIM / TILE, T_TOK / TILE), 256, 0, stream>>>(x, Wp, bp, xp, PDIM, DIN);

  // 2) router + dispatch lists
  router_kernel<<<T_TOK, 64, 0, stream>>>(xp, Wr, br, bc, tidx, tw, counts);
  prefix_kernel<<<1, 64, 0, stream>>>(counts, off, fill);
  build_dispatch<<<T_TOK / 256, 256, 0, stream>>>(tidx, tw, off, fill, tok, wgt);

  const dim3 blk(512), tbk(256);
  const int* NONE_I = nullptr;
  const float* NONE_F = nullptr;

  // ---- shared experts (G/H in GH, in place) ----
  roundtrans<<<dim3(PDIM / 64, ISH / 64, 1), tbk, 0, stream>>>(Wsg, Wpl, PDIM, ISH);
  moe_gemm2<0, 0><<<dim3(ISH / BN, T_TOK / BM), blk, 0, stream>>>(
      xp, Wpl, bsg, 0, GH, NONE_I, NONE_I, NONE_I, NONE_F, nullptr, T_TOK, ISH, PDIM);
  roundtrans<<<dim3(PDIM / 64, ISH / 64, 1), tbk, 0, stream>>>(Wsu, Wpl, PDIM, ISH);
  moe_gemm2<0, 1><<<dim3(ISH / BN, T_TOK / BM), blk, 0, stream>>>(
      xp, Wpl, bsu, 0, GH, NONE_I, NONE_I, NONE_I, NONE_F, nullptr, T_TOK, ISH, PDIM);
  roundtrans<<<dim3(ISH / 64, PDIM / 64, 1), tbk, 0, stream>>>(Wsd, Wpl, ISH, PDIM);
  moe_gemm2<0, 0><<<dim3(PDIM / BN, T_TOK / BM), blk, 0, stream>>>(
      GH, Wpl, bsd, 0, comb, NONE_I, NONE_I, NONE_I, NONE_F, nullptr, T_TOK, PDIM, ISH);

  // ---- routed experts (slots in GH; atomic combine into comb) ----
  roundtrans<<<dim3(PDIM / 64, IDIM / 64, NEXP), tbk, 0, stream>>>(Wg, Wpl, PDIM, IDIM);
  moe_gemm2<1, 0><<<dim3(IDIM / BN, 64, NEXP), blk, 0, stream>>>(
      xp, Wpl, bg, IDIM, GH, off, tok, NONE_I, NONE_F, nullptr, 0, IDIM, PDIM);
  roundtrans<<<dim3(PDIM / 64, IDIM / 64, NEXP), tbk, 0, stream>>>(Wu, Wpl, PDIM, IDIM);
  moe_gemm2<1, 1><<<dim3(IDIM / BN, 64, NEXP), blk, 0, stream>>>(
      xp, Wpl, bu, IDIM, GH, off, tok, NONE_I, NONE_F, nullptr, 0, IDIM, PDIM);
  roundtrans<<<dim3(IDIM / 64, PDIM / 64, NEXP), tbk, 0, stream>>>(Wd, Wpl, IDIM, PDIM);
  moe_gemm2<2, 2><<<dim3(PDIM / BN, 64, NEXP), blk, 0, stream>>>(
      GH, Wpl, bd, PDIM, nullptr, off, NONE_I, tok, wgt, comb, 0, PDIM, IDIM);

  // ---- output MLP: mid = silu(comb @ W1 + b1) into GH; out = mid @ W2 + b2 ----
  roundtrans<<<dim3(PDIM / 64, IDIM / 64, 1), tbk, 0, stream>>>(W1, Wpl, PDIM, IDIM);
  moe_gemm2<0, 3><<<dim3(IDIM / BN, T_TOK / BM), blk, 0, stream>>>(
      comb, Wpl, b1, 0, GH, NONE_I, NONE_I, NONE_I, NONE_F, nullptr, T_TOK, IDIM, PDIM);
  out_mlp2<<<T_TOK / TILE, 256, 0, stream>>>(GH, W2, b2, out);
}